// Round 3
// baseline (234.892 us; speedup 1.0000x reference)
//
#include <hip/hip_runtime.h>
#include <cstdint>
#include <cstddef>

#define N_ROWS 3456   // 16*216 chunks
#define C_DIM 256
#define K_CB 1024
#define B_SZ 16
#define SPATIAL 216
#define VOX 13824     // 24*24*24
#define NCH 32

typedef __attribute__((ext_vector_type(16))) float f32x16;
typedef __attribute__((ext_vector_type(8))) short bf16x8;

// ------------------------------------------- K1: patterns (+ init fused)
__global__ void k_patterns(const float* __restrict__ in,
                           unsigned long long* __restrict__ pats,
                           float* __restrict__ avgp, float* __restrict__ scal) {
    if (blockIdx.x == 0) {
        for (int i = threadIdx.x; i < K_CB; i += 256) avgp[i] = 0.0f;
        if (threadIdx.x < 8) scal[threadIdx.x] = 0.0f;
    }
    int v = blockIdx.x * 256 + threadIdx.x;       // 0..221183
    int b = v / VOX;
    int r = v % VOX;
    const float* p = in + (size_t)b * NCH * VOX + r;
    float v0 = p[0];
    float mx = -INFINITY;
#pragma unroll
    for (int c = 1; c < NCH; ++c) mx = fmaxf(mx, p[(size_t)c * VOX]);
    bool bit = mx > v0;
    unsigned long long m = __ballot(bit);
    if ((threadIdx.x & 63) == 0) pats[v >> 6] = m;
}

// ------------------------------------------------- K2: normalize codebook
__global__ void k_norm_cb(const float* __restrict__ cb, float* __restrict__ en) {
    int k = blockIdx.x, c = threadIdx.x;
    float v = cb[k * C_DIM + c];
    float ss = v * v;
#pragma unroll
    for (int off = 32; off > 0; off >>= 1) ss += __shfl_down(ss, off, 64);
    __shared__ float ws[4];
    if ((c & 63) == 0) ws[c >> 6] = ss;
    __syncthreads();
    float tot = ws[0] + ws[1] + ws[2] + ws[3];
    float nrm = fmaxf(sqrtf(tot), 1e-12f);
    en[k * C_DIM + c] = v / nrm;
}

// ------------------------------ K3: normalize z_e (fp32 + bf16 copies)
__device__ __forceinline__ unsigned short f2bf_rne(float f) {
    unsigned int u = __float_as_uint(f);
    u += 0x7FFFu + ((u >> 16) & 1u);
    return (unsigned short)(u >> 16);
}
__global__ void k_norm_z(const float* __restrict__ ze, float* __restrict__ zn,
                         unsigned short* __restrict__ znb) {
    int n = blockIdx.x, c = threadIdx.x;
    int b = n / SPATIAL, s = n % SPATIAL;
    float v = ze[((size_t)(b * C_DIM + c)) * SPATIAL + s];
    float ss = v * v;
#pragma unroll
    for (int off = 32; off > 0; off >>= 1) ss += __shfl_down(ss, off, 64);
    __shared__ float ws[4];
    if ((c & 63) == 0) ws[c >> 6] = ss;
    __syncthreads();
    float tot = ws[0] + ws[1] + ws[2] + ws[3];
    float nrm = fmaxf(sqrtf(tot), 1e-12f);
    float o = v / nrm;
    zn[n * C_DIM + c] = o;
    znb[n * C_DIM + c] = f2bf_rne(o);
}

// ------------------- K4a: fp32 GEMM aff = zn @ en^T  (3456 x 1024 x 256)
// 64x64 tile, 4x4 micro with rows spaced 16 (round-0-verified conflict-free)
#define GSTR 68
__global__ __launch_bounds__(256) void k_gemm(
        const float* __restrict__ zn, const float* __restrict__ en,
        float* __restrict__ aff) {
    __shared__ __align__(16) float As[64 * GSTR];
    __shared__ __align__(16) float Bs[64 * GSTR];
    int t = threadIdx.x;
    int n0 = blockIdx.x * 64, k0 = blockIdx.y * 64;
    int tx = t & 15, ty = t >> 4;
    float acc[4][4];
#pragma unroll
    for (int r = 0; r < 4; ++r)
#pragma unroll
        for (int q = 0; q < 4; ++q) acc[r][q] = 0.0f;

    for (int ck = 0; ck < 4; ++ck) {
        __syncthreads();
#pragma unroll
        for (int i = 0; i < 4; ++i) {
            int f = i * 256 + t;
            int r = f >> 4, c4 = f & 15;
            *(float4*)&As[r * GSTR + c4 * 4] =
                *(const float4*)&zn[(size_t)(n0 + r) * C_DIM + ck * 64 + c4 * 4];
            *(float4*)&Bs[r * GSTR + c4 * 4] =
                *(const float4*)&en[(size_t)(k0 + r) * C_DIM + ck * 64 + c4 * 4];
        }
        __syncthreads();

#pragma unroll
        for (int c4 = 0; c4 < 16; ++c4) {
            float4 a4[4], b4[4];
#pragma unroll
            for (int r = 0; r < 4; ++r)
                a4[r] = *(const float4*)&As[(ty + 16 * r) * GSTR + c4 * 4];
#pragma unroll
            for (int q = 0; q < 4; ++q)
                b4[q] = *(const float4*)&Bs[(tx + 16 * q) * GSTR + c4 * 4];
#pragma unroll
            for (int r = 0; r < 4; ++r)
#pragma unroll
                for (int q = 0; q < 4; ++q)
                    acc[r][q] += a4[r].x * b4[q].x + a4[r].y * b4[q].y +
                                 a4[r].z * b4[q].z + a4[r].w * b4[q].w;
        }
    }
#pragma unroll
    for (int r = 0; r < 4; ++r)
#pragma unroll
        for (int q = 0; q < 4; ++q)
            aff[(size_t)(n0 + ty + 16 * r) * K_CB + k0 + tx + 16 * q] = acc[r][q];
}

// ---------------- K4b: row softmax stats / argmax from aff (8 rows/block)
__global__ __launch_bounds__(256) void k_stats(
        const float* __restrict__ aff, float* __restrict__ avgp,
        float* __restrict__ scal, int* __restrict__ idx_arr,
        float* __restrict__ out_idx) {
    __shared__ float wv[32], wsum[32], wtum[32];
    __shared__ int   wi[32];
    __shared__ float m8[8], s8[8], t8[8];
    __shared__ int   i8[8];
    int t = threadIdx.x;
    int lane = t & 63, w = t >> 6;
    int n0 = blockIdx.x * 8;
    int k0 = t * 4;

    float av[8][4];
#pragma unroll
    for (int n = 0; n < 8; ++n) {
        float4 v = *(const float4*)&aff[(size_t)(n0 + n) * K_CB + k0];
        av[n][0] = v.x; av[n][1] = v.y; av[n][2] = v.z; av[n][3] = v.w;
    }
    // per-thread then wave-level argmax (first-max tie-break: lower index)
    float lm[8]; int li[8];
#pragma unroll
    for (int n = 0; n < 8; ++n) {
        lm[n] = av[n][0]; li[n] = k0;
#pragma unroll
        for (int i = 1; i < 4; ++i)
            if (av[n][i] > lm[n]) { lm[n] = av[n][i]; li[n] = k0 + i; }
    }
#pragma unroll
    for (int off = 32; off > 0; off >>= 1) {
#pragma unroll
        for (int n = 0; n < 8; ++n) {
            float vo = __shfl_down(lm[n], off, 64);
            int   io = __shfl_down(li[n], off, 64);
            if (vo > lm[n] || (vo == lm[n] && io < li[n])) { lm[n] = vo; li[n] = io; }
        }
    }
    if (lane == 0)
#pragma unroll
        for (int n = 0; n < 8; ++n) { wv[w * 8 + n] = lm[n]; wi[w * 8 + n] = li[n]; }
    __syncthreads();
    if (t < 8) {
        float m = wv[t]; int ii = wi[t];
#pragma unroll
        for (int ww = 1; ww < 4; ++ww) {
            float v2 = wv[ww * 8 + t]; int j2 = wi[ww * 8 + t];
            if (v2 > m || (v2 == m && j2 < ii)) { m = v2; ii = j2; }
        }
        m8[t] = m; i8[t] = ii;
    }
    __syncthreads();

    // exp stats: S = sum e, T = sum e*d  (d = 100*(aff-m))
    float e[8][4], ls[8], lt[8];
#pragma unroll
    for (int n = 0; n < 8; ++n) {
        float m = m8[n], s = 0.0f, tt = 0.0f;
#pragma unroll
        for (int i = 0; i < 4; ++i) {
            float d = 100.0f * (av[n][i] - m);
            float ee = __expf(d);
            e[n][i] = ee; s += ee; tt += ee * d;
        }
        ls[n] = s; lt[n] = tt;
    }
#pragma unroll
    for (int off = 32; off > 0; off >>= 1)
#pragma unroll
        for (int n = 0; n < 8; ++n) {
            ls[n] += __shfl_down(ls[n], off, 64);
            lt[n] += __shfl_down(lt[n], off, 64);
        }
    if (lane == 0)
#pragma unroll
        for (int n = 0; n < 8; ++n) { wsum[w * 8 + n] = ls[n]; wtum[w * 8 + n] = lt[n]; }
    __syncthreads();
    if (t < 8) {
        float s = 0.0f, tt = 0.0f;
#pragma unroll
        for (int ww = 0; ww < 4; ++ww) { s += wsum[ww * 8 + t]; tt += wtum[ww * 8 + t]; }
        s8[t] = s; t8[t] = tt;
    }
    __syncthreads();

    float ps[4] = {0.0f, 0.0f, 0.0f, 0.0f};
#pragma unroll
    for (int n = 0; n < 8; ++n) {
        float inv = 1.0f / s8[n];
#pragma unroll
        for (int i = 0; i < 4; ++i) ps[i] += e[n][i] * inv;
    }
#pragma unroll
    for (int i = 0; i < 4; ++i) atomicAdd(&avgp[k0 + i], ps[i]);
    if (t == 0) {
        float se = 0.0f, cm = 0.0f;
#pragma unroll
        for (int n = 0; n < 8; ++n) {
            se += logf(s8[n]) - t8[n] / s8[n];
            cm += 2.0f - 2.0f * m8[n];
        }
        atomicAdd(&scal[0], se);
        atomicAdd(&scal[1], cm);
    }
    if (t < 8) { idx_arr[n0 + t] = i8[t]; out_idx[n0 + t] = (float)i8[t]; }
}

// ---------------- K5: pairwise Gram via bf16 MFMA, upper-triangular tiles
#define HSTR 72
__global__ __launch_bounds__(128) void k_ham(
        const unsigned short* __restrict__ znb,
        const unsigned long long* __restrict__ pats,
        float* __restrict__ scal) {
    int bid = blockIdx.x;            // 0..377
    int ti = 0, rem = bid;
    while (rem >= 27 - ti) { rem -= 27 - ti; ++ti; }
    int tj = ti + rem;
    int i0 = ti * 128, j0 = tj * 128;
    float factor = (ti == tj) ? 1.0f : 2.0f;

    __shared__ __align__(16) unsigned short zi[128 * HSTR];
    __shared__ __align__(16) unsigned short zj[128 * HSTR];

    int t = threadIdx.x;       // 0..127
    int w = t >> 6;
    int lane = t & 63;

    f32x16 acc[2][4];
#pragma unroll
    for (int a = 0; a < 2; ++a)
#pragma unroll
        for (int b = 0; b < 4; ++b)
#pragma unroll
            for (int e = 0; e < 16; ++e) acc[a][b][e] = 0.0f;

    for (int ck = 0; ck < 4; ++ck) {
        __syncthreads();
#pragma unroll
        for (int p = 0; p < 8; ++p) {
            int row = p * 16 + (t >> 3);
            int seg = t & 7;
            *(float4*)&zi[row * HSTR + seg * 8] =
                *(const float4*)&znb[(size_t)(i0 + row) * C_DIM + ck * 64 + seg * 8];
            *(float4*)&zj[row * HSTR + seg * 8] =
                *(const float4*)&znb[(size_t)(j0 + row) * C_DIM + ck * 64 + seg * 8];
        }
        __syncthreads();

#pragma unroll
        for (int ks = 0; ks < 4; ++ks) {
            int off = (lane & 31) * HSTR + (lane >> 5) * 8 + ks * 16;
            bf16x8 a0 = *(bf16x8*)&zi[(w * 64) * HSTR + off];
            bf16x8 a1 = *(bf16x8*)&zi[(w * 64 + 32) * HSTR + off];
            bf16x8 bf[4];
#pragma unroll
            for (int c = 0; c < 4; ++c)
                bf[c] = *(bf16x8*)&zj[(c * 32) * HSTR + off];
#pragma unroll
            for (int c = 0; c < 4; ++c) {
                acc[0][c] = __builtin_amdgcn_mfma_f32_32x32x16_bf16(a0, bf[c], acc[0][c], 0, 0, 0);
                acc[1][c] = __builtin_amdgcn_mfma_f32_32x32x16_bf16(a1, bf[c], acc[1][c], 0, 0, 0);
            }
        }
    }

    unsigned long long pj[4];
#pragma unroll
    for (int c = 0; c < 4; ++c) pj[c] = pats[j0 + c * 32 + (lane & 31)];

    float sW = 0.0f, sD = 0.0f;
#pragma unroll
    for (int r = 0; r < 2; ++r) {
        int ibase = i0 + w * 64 + r * 32 + 4 * (lane >> 5);
#pragma unroll
        for (int g = 0; g < 16; ++g) {
            int gi = ibase + (g & 3) + 8 * (g >> 2);
            unsigned long long pi = pats[gi];
#pragma unroll
            for (int c = 0; c < 4; ++c) {
                int gj = j0 + c * 32 + (lane & 31);
                int pop = __popcll(pi ^ pj[c]);
                float wgt = (pop <= 5 && gi != gj) ? (1.0f - (float)pop * 0.015625f) : 0.0f;
                sW += wgt;
                sD += wgt * acc[r][c][g];
            }
        }
    }
#pragma unroll
    for (int off = 32; off > 0; off >>= 1) {
        sW += __shfl_down(sW, off, 64);
        sD += __shfl_down(sD, off, 64);
    }
    if (lane == 0) {
        atomicAdd(&scal[2], factor * sW);
        atomicAdd(&scal[3], factor * sD);
    }
}

// --------------------------------------------------- K6: z_q output gather
__global__ void k_zq(const float* __restrict__ en, const int* __restrict__ idx,
                     float* __restrict__ out) {
    int v = blockIdx.x * 256 + threadIdx.x;   // 0..884735
    int b = v / (C_DIM * SPATIAL);
    int rem = v - b * (C_DIM * SPATIAL);
    int c = rem / SPATIAL;
    int s = rem - c * SPATIAL;
    int n = b * SPATIAL + s;
    out[v] = en[(size_t)idx[n] * C_DIM + c];
}

// ------------------------------------------------- K7: final loss combine
__global__ void k_final(const float* __restrict__ avgp,
                        const float* __restrict__ scal,
                        float* __restrict__ out_loss) {
    int t = threadIdx.x;   // 1024 threads
    float ap = avgp[t] * (1.0f / N_ROWS);
    float term = ap * logf(ap + 1e-5f);
#pragma unroll
    for (int off = 32; off > 0; off >>= 1) term += __shfl_down(term, off, 64);
    __shared__ float ws[16];
    if ((t & 63) == 0) ws[t >> 6] = term;
    __syncthreads();
    if (t == 0) {
        float sAP = 0.0f;
#pragma unroll
        for (int i = 0; i < 16; ++i) sAP += ws[i];
        float sample = scal[0] * (1.0f / N_ROWS);
        float commit = scal[1] * (1.0f / ((float)N_ROWS * C_DIM));
        float ent = 0.1f * (sample + sAP);
        float ham = (scal[2] - scal[3]) / (scal[2] + 1e-8f);
        *out_loss = 1.25f * commit + ent + ham;
    }
}

// ----------------------------------------------------------------- launch
extern "C" void kernel_launch(void* const* d_in, const int* in_sizes, int n_in,
                              void* d_out, int out_size, void* d_ws, size_t ws_size,
                              hipStream_t stream) {
    const float* in_blocks = (const float*)d_in[0];  // [16,32,24,24,24]
    const float* z_e       = (const float*)d_in[1];  // [16,256,6,6,6]
    const float* cb        = (const float*)d_in[2];  // [1024,256]
    float* out = (float*)d_out;  // [884736 z_q][1 loss][3456 idx]

    char* ws = (char*)d_ws;
    float* zn   = (float*)(ws + 0);                  //  3,538,944 B
    float* en   = (float*)(ws + 3538944);            //  1,048,576 B
    float* aff  = (float*)(ws + 4587520);            // 14,155,776 B
    unsigned long long* pats = (unsigned long long*)(ws + 18743296); // 27,648 B
    int*   idx  = (int*)(ws + 18770944);             // 13,824 B
    float* avgp = (float*)(ws + 18784768);           //  4,096 B
    float* scal = (float*)(ws + 18788864);           //  64 B
    unsigned short* znb = (unsigned short*)(ws + 18788928); // 1,769,472 B -> 20,558,400 total

    k_patterns<<<864, 256, 0, stream>>>(in_blocks, pats, avgp, scal);
    k_norm_cb<<<1024, 256, 0, stream>>>(cb, en);
    k_norm_z<<<3456, 256, 0, stream>>>(z_e, zn, znb);
    k_gemm<<<dim3(54, 16), 256, 0, stream>>>(zn, en, aff);
    k_stats<<<432, 256, 0, stream>>>(aff, avgp, scal, idx, out + 884737);
    k_ham<<<378, 128, 0, stream>>>(znb, pats, scal);
    k_zq<<<3456, 256, 0, stream>>>(en, idx, out);
    k_final<<<1, 1024, 0, stream>>>(avgp, scal, out + 884736);
}

// Round 4
// 181.874 us; speedup vs baseline: 1.2915x; 1.2915x over previous
//
#include <hip/hip_runtime.h>
#include <cstdint>
#include <cstddef>

#define N_ROWS 3456   // 16*216 chunks
#define C_DIM 256
#define K_CB 1024
#define B_SZ 16
#define SPATIAL 216
#define VOX 13824     // 24*24*24
#define NCH 32

typedef __attribute__((ext_vector_type(16))) float f32x16;
typedef __attribute__((ext_vector_type(8))) short bf16x8;

__device__ __forceinline__ unsigned short f2bf_rne(float f) {
    unsigned int u = __float_as_uint(f);
    u += 0x7FFFu + ((u >> 16) & 1u);
    return (unsigned short)(u >> 16);
}
__device__ __forceinline__ float bf2f(unsigned short h) {
    unsigned int u = ((unsigned int)h) << 16;
    return __uint_as_float(u);
}

// ---------------- K1: fused preprocessing: patterns + init + cb/z norm+split
// grid: [0,864) patterns ; [864,1888) codebook ; [1888,5344) z rows
__global__ __launch_bounds__(256) void k_pre(
        const float* __restrict__ in, const float* __restrict__ cb,
        const float* __restrict__ ze,
        unsigned long long* __restrict__ pats,
        float* __restrict__ avgp, float* __restrict__ scal,
        float* __restrict__ en,
        unsigned short* __restrict__ ehi, unsigned short* __restrict__ elo,
        unsigned short* __restrict__ zhi, unsigned short* __restrict__ zlo) {
    int bid = blockIdx.x;
    int t = threadIdx.x;
    if (bid < 864) {
        if (bid == 0) {
            for (int i = t; i < K_CB; i += 256) avgp[i] = 0.0f;
            if (t < 8) scal[t] = 0.0f;
        }
        int v = bid * 256 + t;
        int b = v / VOX;
        int r = v % VOX;
        const float* p = in + (size_t)b * NCH * VOX + r;
        float v0 = p[0];
        float mx = -INFINITY;
#pragma unroll
        for (int c = 1; c < NCH; ++c) mx = fmaxf(mx, p[(size_t)c * VOX]);
        unsigned long long m = __ballot(mx > v0);
        if ((t & 63) == 0) pats[v >> 6] = m;
        return;
    }
    __shared__ float ws[4];
    if (bid < 1888) {
        int k = bid - 864, c = t;
        float v = cb[k * C_DIM + c];
        float ss = v * v;
#pragma unroll
        for (int off = 32; off > 0; off >>= 1) ss += __shfl_down(ss, off, 64);
        if ((c & 63) == 0) ws[c >> 6] = ss;
        __syncthreads();
        float nrm = fmaxf(sqrtf(ws[0] + ws[1] + ws[2] + ws[3]), 1e-12f);
        float o = v / nrm;
        en[k * C_DIM + c] = o;
        unsigned short h = f2bf_rne(o);
        ehi[k * C_DIM + c] = h;
        elo[k * C_DIM + c] = f2bf_rne(o - bf2f(h));
    } else {
        int n = bid - 1888, c = t;
        int b = n / SPATIAL, s = n % SPATIAL;
        float v = ze[((size_t)(b * C_DIM + c)) * SPATIAL + s];
        float ss = v * v;
#pragma unroll
        for (int off = 32; off > 0; off >>= 1) ss += __shfl_down(ss, off, 64);
        if ((c & 63) == 0) ws[c >> 6] = ss;
        __syncthreads();
        float nrm = fmaxf(sqrtf(ws[0] + ws[1] + ws[2] + ws[3]), 1e-12f);
        float o = v / nrm;
        unsigned short h = f2bf_rne(o);
        zhi[n * C_DIM + c] = h;
        zlo[n * C_DIM + c] = f2bf_rne(o - bf2f(h));
    }
}

// ------------- K2: affinity GEMM via bf16x3 MFMA: aff = z @ en^T (fp32-class)
// 64(i) x 128(j) tile, 2 waves (one j-half each), acc 2x2 of 32x32.
#define GS 72
__global__ __launch_bounds__(128) void k_gemm(
        const unsigned short* __restrict__ zhi, const unsigned short* __restrict__ zlo,
        const unsigned short* __restrict__ ehi, const unsigned short* __restrict__ elo,
        float* __restrict__ aff) {
    __shared__ __align__(16) unsigned short Ah[64 * GS], Al[64 * GS];
    __shared__ __align__(16) unsigned short Bh[128 * GS], Bl[128 * GS];
    int t = threadIdx.x;
    int w = t >> 6, lane = t & 63;
    int i0 = blockIdx.x * 64, j0 = blockIdx.y * 128;

    f32x16 acc[2][2];
#pragma unroll
    for (int r = 0; r < 2; ++r)
#pragma unroll
        for (int q = 0; q < 2; ++q)
#pragma unroll
            for (int e = 0; e < 16; ++e) acc[r][q][e] = 0.0f;

    for (int ck = 0; ck < 4; ++ck) {
        __syncthreads();
#pragma unroll
        for (int l = 0; l < 4; ++l) {          // A: 64 rows x 8 segs of 16B
            int s = l * 128 + t;
            int row = s >> 3, c8 = s & 7;
            *(float4*)&Ah[row * GS + c8 * 8] =
                *(const float4*)&zhi[(size_t)(i0 + row) * C_DIM + ck * 64 + c8 * 8];
            *(float4*)&Al[row * GS + c8 * 8] =
                *(const float4*)&zlo[(size_t)(i0 + row) * C_DIM + ck * 64 + c8 * 8];
        }
#pragma unroll
        for (int l = 0; l < 8; ++l) {          // B: 128 rows x 8 segs
            int s = l * 128 + t;
            int row = s >> 3, c8 = s & 7;
            *(float4*)&Bh[row * GS + c8 * 8] =
                *(const float4*)&ehi[(size_t)(j0 + row) * C_DIM + ck * 64 + c8 * 8];
            *(float4*)&Bl[row * GS + c8 * 8] =
                *(const float4*)&elo[(size_t)(j0 + row) * C_DIM + ck * 64 + c8 * 8];
        }
        __syncthreads();

#pragma unroll
        for (int ks = 0; ks < 4; ++ks) {
            int koff = (lane >> 5) * 8 + ks * 16;
            bf16x8 ah[2], al[2], bh[2], bl[2];
#pragma unroll
            for (int r = 0; r < 2; ++r) {
                ah[r] = *(bf16x8*)&Ah[(r * 32 + (lane & 31)) * GS + koff];
                al[r] = *(bf16x8*)&Al[(r * 32 + (lane & 31)) * GS + koff];
            }
#pragma unroll
            for (int q = 0; q < 2; ++q) {
                bh[q] = *(bf16x8*)&Bh[(w * 64 + q * 32 + (lane & 31)) * GS + koff];
                bl[q] = *(bf16x8*)&Bl[(w * 64 + q * 32 + (lane & 31)) * GS + koff];
            }
#pragma unroll
            for (int r = 0; r < 2; ++r)
#pragma unroll
                for (int q = 0; q < 2; ++q) {
                    acc[r][q] = __builtin_amdgcn_mfma_f32_32x32x16_bf16(ah[r], bh[q], acc[r][q], 0, 0, 0);
                    acc[r][q] = __builtin_amdgcn_mfma_f32_32x32x16_bf16(ah[r], bl[q], acc[r][q], 0, 0, 0);
                    acc[r][q] = __builtin_amdgcn_mfma_f32_32x32x16_bf16(al[r], bh[q], acc[r][q], 0, 0, 0);
                }
        }
    }
    // C/D layout (m74/m101-verified): col=lane&31, row=(g&3)+8*(g>>2)+4*(lane>>5)
#pragma unroll
    for (int r = 0; r < 2; ++r)
#pragma unroll
        for (int q = 0; q < 2; ++q)
#pragma unroll
            for (int g = 0; g < 16; ++g) {
                int row = i0 + r * 32 + (g & 3) + 8 * (g >> 2) + 4 * (lane >> 5);
                int col = j0 + w * 64 + q * 32 + (lane & 31);
                aff[(size_t)row * K_CB + col] = acc[r][q][g];
            }
}

// ---------------- K3: row softmax stats / argmax from aff (8 rows/block)
__global__ __launch_bounds__(256) void k_stats(
        const float* __restrict__ aff, float* __restrict__ avgp,
        float* __restrict__ scal, int* __restrict__ idx_arr,
        float* __restrict__ out_idx) {
    __shared__ float wv[32], wsum[32], wtum[32];
    __shared__ int   wi[32];
    __shared__ float m8[8], s8[8], t8[8];
    __shared__ int   i8[8];
    int t = threadIdx.x;
    int lane = t & 63, w = t >> 6;
    int n0 = blockIdx.x * 8;
    int k0 = t * 4;

    float av[8][4];
#pragma unroll
    for (int n = 0; n < 8; ++n) {
        float4 v = *(const float4*)&aff[(size_t)(n0 + n) * K_CB + k0];
        av[n][0] = v.x; av[n][1] = v.y; av[n][2] = v.z; av[n][3] = v.w;
    }
    float lm[8]; int li[8];
#pragma unroll
    for (int n = 0; n < 8; ++n) {
        lm[n] = av[n][0]; li[n] = k0;
#pragma unroll
        for (int i = 1; i < 4; ++i)
            if (av[n][i] > lm[n]) { lm[n] = av[n][i]; li[n] = k0 + i; }
    }
#pragma unroll
    for (int off = 32; off > 0; off >>= 1) {
#pragma unroll
        for (int n = 0; n < 8; ++n) {
            float vo = __shfl_down(lm[n], off, 64);
            int   io = __shfl_down(li[n], off, 64);
            if (vo > lm[n] || (vo == lm[n] && io < li[n])) { lm[n] = vo; li[n] = io; }
        }
    }
    if (lane == 0)
#pragma unroll
        for (int n = 0; n < 8; ++n) { wv[w * 8 + n] = lm[n]; wi[w * 8 + n] = li[n]; }
    __syncthreads();
    if (t < 8) {
        float m = wv[t]; int ii = wi[t];
#pragma unroll
        for (int ww = 1; ww < 4; ++ww) {
            float v2 = wv[ww * 8 + t]; int j2 = wi[ww * 8 + t];
            if (v2 > m || (v2 == m && j2 < ii)) { m = v2; ii = j2; }
        }
        m8[t] = m; i8[t] = ii;
    }
    __syncthreads();

    float e[8][4], ls[8], lt[8];
#pragma unroll
    for (int n = 0; n < 8; ++n) {
        float m = m8[n], s = 0.0f, tt = 0.0f;
#pragma unroll
        for (int i = 0; i < 4; ++i) {
            float d = 100.0f * (av[n][i] - m);
            float ee = __expf(d);
            e[n][i] = ee; s += ee; tt += ee * d;
        }
        ls[n] = s; lt[n] = tt;
    }
#pragma unroll
    for (int off = 32; off > 0; off >>= 1)
#pragma unroll
        for (int n = 0; n < 8; ++n) {
            ls[n] += __shfl_down(ls[n], off, 64);
            lt[n] += __shfl_down(lt[n], off, 64);
        }
    if (lane == 0)
#pragma unroll
        for (int n = 0; n < 8; ++n) { wsum[w * 8 + n] = ls[n]; wtum[w * 8 + n] = lt[n]; }
    __syncthreads();
    if (t < 8) {
        float s = 0.0f, tt = 0.0f;
#pragma unroll
        for (int ww = 0; ww < 4; ++ww) { s += wsum[ww * 8 + t]; tt += wtum[ww * 8 + t]; }
        s8[t] = s; t8[t] = tt;
    }
    __syncthreads();

    float ps[4] = {0.0f, 0.0f, 0.0f, 0.0f};
#pragma unroll
    for (int n = 0; n < 8; ++n) {
        float inv = 1.0f / s8[n];
#pragma unroll
        for (int i = 0; i < 4; ++i) ps[i] += e[n][i] * inv;
    }
#pragma unroll
    for (int i = 0; i < 4; ++i) atomicAdd(&avgp[k0 + i], ps[i]);
    if (t == 0) {
        float se = 0.0f, cm = 0.0f;
#pragma unroll
        for (int n = 0; n < 8; ++n) {
            se += logf(s8[n]) - t8[n] / s8[n];
            cm += 2.0f - 2.0f * m8[n];
        }
        atomicAdd(&scal[0], se);
        atomicAdd(&scal[1], cm);
    }
    if (t < 8) { idx_arr[n0 + t] = i8[t]; out_idx[n0 + t] = (float)i8[t]; }
}

// ---------------- K4: pairwise Gram via bf16 MFMA, upper-triangular tiles
#define HSTR 72
__global__ __launch_bounds__(128) void k_ham(
        const unsigned short* __restrict__ znb,
        const unsigned long long* __restrict__ pats,
        float* __restrict__ scal) {
    int bid = blockIdx.x;            // 0..377
    int ti = 0, rem = bid;
    while (rem >= 27 - ti) { rem -= 27 - ti; ++ti; }
    int tj = ti + rem;
    int i0 = ti * 128, j0 = tj * 128;
    float factor = (ti == tj) ? 1.0f : 2.0f;

    __shared__ __align__(16) unsigned short zi[128 * HSTR];
    __shared__ __align__(16) unsigned short zj[128 * HSTR];

    int t = threadIdx.x;
    int w = t >> 6;
    int lane = t & 63;

    f32x16 acc[2][4];
#pragma unroll
    for (int a = 0; a < 2; ++a)
#pragma unroll
        for (int b = 0; b < 4; ++b)
#pragma unroll
            for (int e = 0; e < 16; ++e) acc[a][b][e] = 0.0f;

    for (int ck = 0; ck < 4; ++ck) {
        __syncthreads();
#pragma unroll
        for (int p = 0; p < 8; ++p) {
            int row = p * 16 + (t >> 3);
            int seg = t & 7;
            *(float4*)&zi[row * HSTR + seg * 8] =
                *(const float4*)&znb[(size_t)(i0 + row) * C_DIM + ck * 64 + seg * 8];
            *(float4*)&zj[row * HSTR + seg * 8] =
                *(const float4*)&znb[(size_t)(j0 + row) * C_DIM + ck * 64 + seg * 8];
        }
        __syncthreads();

#pragma unroll
        for (int ks = 0; ks < 4; ++ks) {
            int off = (lane & 31) * HSTR + (lane >> 5) * 8 + ks * 16;
            bf16x8 a0 = *(bf16x8*)&zi[(w * 64) * HSTR + off];
            bf16x8 a1 = *(bf16x8*)&zi[(w * 64 + 32) * HSTR + off];
            bf16x8 bf[4];
#pragma unroll
            for (int c = 0; c < 4; ++c)
                bf[c] = *(bf16x8*)&zj[(c * 32) * HSTR + off];
#pragma unroll
            for (int c = 0; c < 4; ++c) {
                acc[0][c] = __builtin_amdgcn_mfma_f32_32x32x16_bf16(a0, bf[c], acc[0][c], 0, 0, 0);
                acc[1][c] = __builtin_amdgcn_mfma_f32_32x32x16_bf16(a1, bf[c], acc[1][c], 0, 0, 0);
            }
        }
    }

    unsigned long long pj[4];
#pragma unroll
    for (int c = 0; c < 4; ++c) pj[c] = pats[j0 + c * 32 + (lane & 31)];

    float sW = 0.0f, sD = 0.0f;
#pragma unroll
    for (int r = 0; r < 2; ++r) {
        int ibase = i0 + w * 64 + r * 32 + 4 * (lane >> 5);
#pragma unroll
        for (int g = 0; g < 16; ++g) {
            int gi = ibase + (g & 3) + 8 * (g >> 2);
            unsigned long long pi = pats[gi];
#pragma unroll
            for (int c = 0; c < 4; ++c) {
                int gj = j0 + c * 32 + (lane & 31);
                int pop = __popcll(pi ^ pj[c]);
                float wgt = (pop <= 5 && gi != gj) ? (1.0f - (float)pop * 0.015625f) : 0.0f;
                sW += wgt;
                sD += wgt * acc[r][c][g];
            }
        }
    }
#pragma unroll
    for (int off = 32; off > 0; off >>= 1) {
        sW += __shfl_down(sW, off, 64);
        sD += __shfl_down(sD, off, 64);
    }
    if (lane == 0) {
        atomicAdd(&scal[2], factor * sW);
        atomicAdd(&scal[3], factor * sD);
    }
}

// ------------------- K5: z_q output gather + (block 0) final loss combine
__global__ __launch_bounds__(256) void k_zq_final(
        const float* __restrict__ en, const int* __restrict__ idx,
        const float* __restrict__ avgp, const float* __restrict__ scal,
        float* __restrict__ out) {
    int t = threadIdx.x;
    int v = blockIdx.x * 256 + t;   // 0..884735
    int b = v / (C_DIM * SPATIAL);
    int rem = v - b * (C_DIM * SPATIAL);
    int c = rem / SPATIAL;
    int s = rem - c * SPATIAL;
    int n = b * SPATIAL + s;
    out[v] = en[(size_t)idx[n] * C_DIM + c];

    if (blockIdx.x == 0) {
        float term = 0.0f;
#pragma unroll
        for (int j = 0; j < 4; ++j) {
            float ap = avgp[t + 256 * j] * (1.0f / N_ROWS);
            term += ap * logf(ap + 1e-5f);
        }
#pragma unroll
        for (int off = 32; off > 0; off >>= 1) term += __shfl_down(term, off, 64);
        __shared__ float ws[4];
        if ((t & 63) == 0) ws[t >> 6] = term;
        __syncthreads();
        if (t == 0) {
            float sAP = ws[0] + ws[1] + ws[2] + ws[3];
            float sample = scal[0] * (1.0f / N_ROWS);
            float commit = scal[1] * (1.0f / ((float)N_ROWS * C_DIM));
            float ent = 0.1f * (sample + sAP);
            float ham = (scal[2] - scal[3]) / (scal[2] + 1e-8f);
            out[884736] = 1.25f * commit + ent + ham;
        }
    }
}

// ----------------------------------------------------------------- launch
extern "C" void kernel_launch(void* const* d_in, const int* in_sizes, int n_in,
                              void* d_out, int out_size, void* d_ws, size_t ws_size,
                              hipStream_t stream) {
    const float* in_blocks = (const float*)d_in[0];  // [16,32,24,24,24]
    const float* z_e       = (const float*)d_in[1];  // [16,256,6,6,6]
    const float* cb        = (const float*)d_in[2];  // [1024,256]
    float* out = (float*)d_out;  // [884736 z_q][1 loss][3456 idx]

    char* ws = (char*)d_ws;
    float* en   = (float*)(ws + 0);                  //  1,048,576 B
    float* aff  = (float*)(ws + 1048576);            // 14,155,776 B
    unsigned short* zhi = (unsigned short*)(ws + 15204352);  // 1,769,472 B
    unsigned short* zlo = (unsigned short*)(ws + 16973824);  // 1,769,472 B
    unsigned short* ehi = (unsigned short*)(ws + 18743296);  //   524,288 B
    unsigned short* elo = (unsigned short*)(ws + 19267584);  //   524,288 B
    unsigned long long* pats = (unsigned long long*)(ws + 19791872); // 27,648 B
    int*   idx  = (int*)(ws + 19819520);             // 13,824 B
    float* avgp = (float*)(ws + 19833344);           //  4,096 B
    float* scal = (float*)(ws + 19837440);           //  64 B

    k_pre<<<5344, 256, 0, stream>>>(in_blocks, cb, z_e, pats, avgp, scal,
                                    en, ehi, elo, zhi, zlo);
    k_gemm<<<dim3(54, 8), 128, 0, stream>>>(zhi, zlo, ehi, elo, aff);
    k_stats<<<432, 256, 0, stream>>>(aff, avgp, scal, idx, out + 884737);
    k_ham<<<378, 128, 0, stream>>>(zhi, pats, scal);
    k_zq_final<<<3456, 256, 0, stream>>>(en, idx, avgp, scal, out);
}

// Round 5
// 163.357 us; speedup vs baseline: 1.4379x; 1.1134x over previous
//
#include <hip/hip_runtime.h>
#include <cstdint>
#include <cstddef>

#define N_ROWS 3456   // 16*216 chunks
#define C_DIM 256
#define K_CB 1024
#define B_SZ 16
#define SPATIAL 216
#define VOX 13824     // 24*24*24
#define NCH 32
#define NSB 54        // k_stats blocks (64 rows each)

typedef __attribute__((ext_vector_type(16))) float f32x16;
typedef __attribute__((ext_vector_type(8))) short bf16x8;

__device__ __forceinline__ unsigned short f2bf_rne(float f) {
    unsigned int u = __float_as_uint(f);
    u += 0x7FFFu + ((u >> 16) & 1u);
    return (unsigned short)(u >> 16);
}
__device__ __forceinline__ float bf2f(unsigned short h) {
    unsigned int u = ((unsigned int)h) << 16;
    return __uint_as_float(u);
}

// ---------------- K1: fused preprocessing: patterns + init + cb/z norm+split
// grid: [0,864) patterns ; [864,1888) codebook ; [1888,5344) z rows
__global__ __launch_bounds__(256) void k_pre(
        const float* __restrict__ in, const float* __restrict__ cb,
        const float* __restrict__ ze,
        unsigned long long* __restrict__ pats,
        float* __restrict__ scal,
        float* __restrict__ en,
        unsigned short* __restrict__ ehi, unsigned short* __restrict__ elo,
        unsigned short* __restrict__ zhi, unsigned short* __restrict__ zlo) {
    int bid = blockIdx.x;
    int t = threadIdx.x;
    if (bid < 864) {
        if (bid == 0 && t < 8) scal[t] = 0.0f;
        int v = bid * 256 + t;
        int b = v / VOX;
        int r = v % VOX;
        const float* p = in + (size_t)b * NCH * VOX + r;
        float v0 = p[0];
        float mx = -INFINITY;
#pragma unroll
        for (int c = 1; c < NCH; ++c) mx = fmaxf(mx, p[(size_t)c * VOX]);
        unsigned long long m = __ballot(mx > v0);
        if ((t & 63) == 0) pats[v >> 6] = m;
        return;
    }
    __shared__ float ws[4];
    if (bid < 1888) {
        int k = bid - 864, c = t;
        float v = cb[k * C_DIM + c];
        float ss = v * v;
#pragma unroll
        for (int off = 32; off > 0; off >>= 1) ss += __shfl_down(ss, off, 64);
        if ((c & 63) == 0) ws[c >> 6] = ss;
        __syncthreads();
        float nrm = fmaxf(sqrtf(ws[0] + ws[1] + ws[2] + ws[3]), 1e-12f);
        float o = v / nrm;
        en[k * C_DIM + c] = o;
        unsigned short h = f2bf_rne(o);
        ehi[k * C_DIM + c] = h;
        elo[k * C_DIM + c] = f2bf_rne(o - bf2f(h));
    } else {
        int n = bid - 1888, c = t;
        int b = n / SPATIAL, s = n % SPATIAL;
        float v = ze[((size_t)(b * C_DIM + c)) * SPATIAL + s];
        float ss = v * v;
#pragma unroll
        for (int off = 32; off > 0; off >>= 1) ss += __shfl_down(ss, off, 64);
        if ((c & 63) == 0) ws[c >> 6] = ss;
        __syncthreads();
        float nrm = fmaxf(sqrtf(ws[0] + ws[1] + ws[2] + ws[3]), 1e-12f);
        float o = v / nrm;
        unsigned short h = f2bf_rne(o);
        zhi[n * C_DIM + c] = h;
        zlo[n * C_DIM + c] = f2bf_rne(o - bf2f(h));
    }
}

// ------------- K2: affinity GEMM via bf16x3 MFMA: aff = z @ en^T (fp32-class)
#define GS 72
__global__ __launch_bounds__(128) void k_gemm(
        const unsigned short* __restrict__ zhi, const unsigned short* __restrict__ zlo,
        const unsigned short* __restrict__ ehi, const unsigned short* __restrict__ elo,
        float* __restrict__ aff) {
    __shared__ __align__(16) unsigned short Ah[64 * GS], Al[64 * GS];
    __shared__ __align__(16) unsigned short Bh[128 * GS], Bl[128 * GS];
    int t = threadIdx.x;
    int w = t >> 6, lane = t & 63;
    int i0 = blockIdx.x * 64, j0 = blockIdx.y * 128;

    f32x16 acc[2][2];
#pragma unroll
    for (int r = 0; r < 2; ++r)
#pragma unroll
        for (int q = 0; q < 2; ++q)
#pragma unroll
            for (int e = 0; e < 16; ++e) acc[r][q][e] = 0.0f;

    for (int ck = 0; ck < 4; ++ck) {
        __syncthreads();
#pragma unroll
        for (int l = 0; l < 4; ++l) {          // A: 64 rows x 8 segs of 16B
            int s = l * 128 + t;
            int row = s >> 3, c8 = s & 7;
            *(float4*)&Ah[row * GS + c8 * 8] =
                *(const float4*)&zhi[(size_t)(i0 + row) * C_DIM + ck * 64 + c8 * 8];
            *(float4*)&Al[row * GS + c8 * 8] =
                *(const float4*)&zlo[(size_t)(i0 + row) * C_DIM + ck * 64 + c8 * 8];
        }
#pragma unroll
        for (int l = 0; l < 8; ++l) {          // B: 128 rows x 8 segs
            int s = l * 128 + t;
            int row = s >> 3, c8 = s & 7;
            *(float4*)&Bh[row * GS + c8 * 8] =
                *(const float4*)&ehi[(size_t)(j0 + row) * C_DIM + ck * 64 + c8 * 8];
            *(float4*)&Bl[row * GS + c8 * 8] =
                *(const float4*)&elo[(size_t)(j0 + row) * C_DIM + ck * 64 + c8 * 8];
        }
        __syncthreads();

#pragma unroll
        for (int ks = 0; ks < 4; ++ks) {
            int koff = (lane >> 5) * 8 + ks * 16;
            bf16x8 ah[2], al[2], bh[2], bl[2];
#pragma unroll
            for (int r = 0; r < 2; ++r) {
                ah[r] = *(bf16x8*)&Ah[(r * 32 + (lane & 31)) * GS + koff];
                al[r] = *(bf16x8*)&Al[(r * 32 + (lane & 31)) * GS + koff];
            }
#pragma unroll
            for (int q = 0; q < 2; ++q) {
                bh[q] = *(bf16x8*)&Bh[(w * 64 + q * 32 + (lane & 31)) * GS + koff];
                bl[q] = *(bf16x8*)&Bl[(w * 64 + q * 32 + (lane & 31)) * GS + koff];
            }
#pragma unroll
            for (int r = 0; r < 2; ++r)
#pragma unroll
                for (int q = 0; q < 2; ++q) {
                    acc[r][q] = __builtin_amdgcn_mfma_f32_32x32x16_bf16(ah[r], bh[q], acc[r][q], 0, 0, 0);
                    acc[r][q] = __builtin_amdgcn_mfma_f32_32x32x16_bf16(ah[r], bl[q], acc[r][q], 0, 0, 0);
                    acc[r][q] = __builtin_amdgcn_mfma_f32_32x32x16_bf16(al[r], bh[q], acc[r][q], 0, 0, 0);
                }
        }
    }
    // C/D layout (m74/m101-verified): col=lane&31, row=(g&3)+8*(g>>2)+4*(lane>>5)
#pragma unroll
    for (int r = 0; r < 2; ++r)
#pragma unroll
        for (int q = 0; q < 2; ++q)
#pragma unroll
            for (int g = 0; g < 16; ++g) {
                int row = i0 + r * 32 + (g & 3) + 8 * (g >> 2) + 4 * (lane >> 5);
                int col = j0 + w * 64 + q * 32 + (lane & 31);
                aff[(size_t)row * K_CB + col] = acc[r][q][g];
            }
}

// ---------------- K3: row stats — 54 blocks x 64 rows, one wave = 16 rows.
// Lane owns cols {j*256 + lane*4 + i}; avgp written as per-block partials
// (plain stores) — no global atomics on the 4 KB footprint.
__global__ __launch_bounds__(256) void k_stats(
        const float* __restrict__ aff, float* __restrict__ avgp_part,
        float* __restrict__ scal, int* __restrict__ idx_arr,
        float* __restrict__ out_idx) {
    __shared__ float lps[4][K_CB];   // 16 KB
    __shared__ float lsc[8];
    int t = threadIdx.x;
    int lane = t & 63, w = t >> 6;
    int n0 = blockIdx.x * 64 + w * 16;

    float ps[16];
#pragma unroll
    for (int i = 0; i < 16; ++i) ps[i] = 0.0f;
    float se = 0.0f, cm = 0.0f;

    for (int r = 0; r < 16; ++r) {
        int row = n0 + r;
        const float* ap = aff + (size_t)row * K_CB;
        float4 v[4];
#pragma unroll
        for (int j = 0; j < 4; ++j)
            v[j] = *(const float4*)&ap[j * 256 + lane * 4];

        // local argmax in increasing-col order (first-max wins via strict >)
        float m = v[0].x; int mi = lane * 4;
#pragma unroll
        for (int j = 0; j < 4; ++j)
#pragma unroll
            for (int i = 0; i < 4; ++i) {
                float x = ((const float*)&v[j])[i];
                int col = j * 256 + lane * 4 + i;
                if (x > m) { m = x; mi = col; }
            }
        // wave argmax (tiebreak: lower col)
#pragma unroll
        for (int off = 32; off > 0; off >>= 1) {
            float vo = __shfl_down(m, off, 64);
            int   io = __shfl_down(mi, off, 64);
            if (vo > m || (vo == m && io < mi)) { m = vo; mi = io; }
        }
        m = __shfl(m, 0, 64);
        mi = __shfl(mi, 0, 64);

        // exp stats
        float e[16];
        float S = 0.0f, T = 0.0f;
#pragma unroll
        for (int j = 0; j < 4; ++j)
#pragma unroll
            for (int i = 0; i < 4; ++i) {
                float d = 100.0f * (((const float*)&v[j])[i] - m);
                float ee = __expf(d);
                e[j * 4 + i] = ee; S += ee; T += ee * d;
            }
#pragma unroll
        for (int off = 32; off > 0; off >>= 1) {
            S += __shfl_down(S, off, 64);
            T += __shfl_down(T, off, 64);
        }
        S = __shfl(S, 0, 64);
        T = __shfl(T, 0, 64);
        float invS = 1.0f / S;
#pragma unroll
        for (int i = 0; i < 16; ++i) ps[i] += e[i] * invS;
        se += logf(S) - T * invS;
        cm += 2.0f - 2.0f * m;
        if (lane == 0) { idx_arr[row] = mi; out_idx[row] = (float)mi; }
    }

    // aggregate ps across the 4 waves in LDS, one plain store per block
#pragma unroll
    for (int j = 0; j < 4; ++j)
#pragma unroll
        for (int i = 0; i < 4; ++i)
            lps[w][j * 256 + lane * 4 + i] = ps[j * 4 + i];
    if (lane == 0) { lsc[w] = se; lsc[4 + w] = cm; }
    __syncthreads();
#pragma unroll
    for (int c = 0; c < 4; ++c) {
        int col = t * 4 + c;
        avgp_part[(size_t)blockIdx.x * K_CB + col] =
            lps[0][col] + lps[1][col] + lps[2][col] + lps[3][col];
    }
    if (t == 0) atomicAdd(&scal[0], lsc[0] + lsc[1] + lsc[2] + lsc[3]);
    if (t == 1) atomicAdd(&scal[1], lsc[4] + lsc[5] + lsc[6] + lsc[7]);
}

// ---------------- K4: pairwise Gram via bf16 MFMA, upper-triangular tiles
#define HSTR 72
__global__ __launch_bounds__(128) void k_ham(
        const unsigned short* __restrict__ znb,
        const unsigned long long* __restrict__ pats,
        float* __restrict__ scal) {
    int bid = blockIdx.x;            // 0..377
    int ti = 0, rem = bid;
    while (rem >= 27 - ti) { rem -= 27 - ti; ++ti; }
    int tj = ti + rem;
    int i0 = ti * 128, j0 = tj * 128;
    float factor = (ti == tj) ? 1.0f : 2.0f;

    __shared__ __align__(16) unsigned short zi[128 * HSTR];
    __shared__ __align__(16) unsigned short zj[128 * HSTR];

    int t = threadIdx.x;
    int w = t >> 6;
    int lane = t & 63;

    f32x16 acc[2][4];
#pragma unroll
    for (int a = 0; a < 2; ++a)
#pragma unroll
        for (int b = 0; b < 4; ++b)
#pragma unroll
            for (int e = 0; e < 16; ++e) acc[a][b][e] = 0.0f;

    for (int ck = 0; ck < 4; ++ck) {
        __syncthreads();
#pragma unroll
        for (int p = 0; p < 8; ++p) {
            int row = p * 16 + (t >> 3);
            int seg = t & 7;
            *(float4*)&zi[row * HSTR + seg * 8] =
                *(const float4*)&znb[(size_t)(i0 + row) * C_DIM + ck * 64 + seg * 8];
            *(float4*)&zj[row * HSTR + seg * 8] =
                *(const float4*)&znb[(size_t)(j0 + row) * C_DIM + ck * 64 + seg * 8];
        }
        __syncthreads();

#pragma unroll
        for (int ks = 0; ks < 4; ++ks) {
            int off = (lane & 31) * HSTR + (lane >> 5) * 8 + ks * 16;
            bf16x8 a0 = *(bf16x8*)&zi[(w * 64) * HSTR + off];
            bf16x8 a1 = *(bf16x8*)&zi[(w * 64 + 32) * HSTR + off];
            bf16x8 bf[4];
#pragma unroll
            for (int c = 0; c < 4; ++c)
                bf[c] = *(bf16x8*)&zj[(c * 32) * HSTR + off];
#pragma unroll
            for (int c = 0; c < 4; ++c) {
                acc[0][c] = __builtin_amdgcn_mfma_f32_32x32x16_bf16(a0, bf[c], acc[0][c], 0, 0, 0);
                acc[1][c] = __builtin_amdgcn_mfma_f32_32x32x16_bf16(a1, bf[c], acc[1][c], 0, 0, 0);
            }
        }
    }

    unsigned long long pj[4];
#pragma unroll
    for (int c = 0; c < 4; ++c) pj[c] = pats[j0 + c * 32 + (lane & 31)];

    float sW = 0.0f, sD = 0.0f;
#pragma unroll
    for (int r = 0; r < 2; ++r) {
        int ibase = i0 + w * 64 + r * 32 + 4 * (lane >> 5);
#pragma unroll
        for (int g = 0; g < 16; ++g) {
            int gi = ibase + (g & 3) + 8 * (g >> 2);
            unsigned long long pi = pats[gi];
#pragma unroll
            for (int c = 0; c < 4; ++c) {
                int gj = j0 + c * 32 + (lane & 31);
                int pop = __popcll(pi ^ pj[c]);
                float wgt = (pop <= 5 && gi != gj) ? (1.0f - (float)pop * 0.015625f) : 0.0f;
                sW += wgt;
                sD += wgt * acc[r][c][g];
            }
        }
    }
#pragma unroll
    for (int off = 32; off > 0; off >>= 1) {
        sW += __shfl_down(sW, off, 64);
        sD += __shfl_down(sD, off, 64);
    }
    if (lane == 0) {
        atomicAdd(&scal[2], factor * sW);
        atomicAdd(&scal[3], factor * sD);
    }
}

// ------------------- K5: z_q output gather + (block 0) final loss combine
__global__ __launch_bounds__(256) void k_zq_final(
        const float* __restrict__ en, const int* __restrict__ idx,
        const float* __restrict__ avgp_part, const float* __restrict__ scal,
        float* __restrict__ out) {
    int t = threadIdx.x;
    int v = blockIdx.x * 256 + t;   // 0..884735
    int b = v / (C_DIM * SPATIAL);
    int rem = v - b * (C_DIM * SPATIAL);
    int c = rem / SPATIAL;
    int s = rem - c * SPATIAL;
    int n = b * SPATIAL + s;
    out[v] = en[(size_t)idx[n] * C_DIM + c];

    if (blockIdx.x == 0) {
        float term = 0.0f;
#pragma unroll
        for (int j = 0; j < 4; ++j) {
            int col = t + 256 * j;
            float ap = 0.0f;
            for (int bb = 0; bb < NSB; ++bb)
                ap += avgp_part[(size_t)bb * K_CB + col];
            ap *= (1.0f / N_ROWS);
            term += ap * logf(ap + 1e-5f);
        }
#pragma unroll
        for (int off = 32; off > 0; off >>= 1) term += __shfl_down(term, off, 64);
        __shared__ float ws[4];
        if ((t & 63) == 0) ws[t >> 6] = term;
        __syncthreads();
        if (t == 0) {
            float sAP = ws[0] + ws[1] + ws[2] + ws[3];
            float sample = scal[0] * (1.0f / N_ROWS);
            float commit = scal[1] * (1.0f / ((float)N_ROWS * C_DIM));
            float ent = 0.1f * (sample + sAP);
            float ham = (scal[2] - scal[3]) / (scal[2] + 1e-8f);
            out[884736] = 1.25f * commit + ent + ham;
        }
    }
}

// ----------------------------------------------------------------- launch
extern "C" void kernel_launch(void* const* d_in, const int* in_sizes, int n_in,
                              void* d_out, int out_size, void* d_ws, size_t ws_size,
                              hipStream_t stream) {
    const float* in_blocks = (const float*)d_in[0];  // [16,32,24,24,24]
    const float* z_e       = (const float*)d_in[1];  // [16,256,6,6,6]
    const float* cb        = (const float*)d_in[2];  // [1024,256]
    float* out = (float*)d_out;  // [884736 z_q][1 loss][3456 idx]

    char* ws = (char*)d_ws;
    float* en   = (float*)(ws + 0);                  //  1,048,576 B
    float* aff  = (float*)(ws + 1048576);            // 14,155,776 B
    unsigned short* zhi = (unsigned short*)(ws + 15204352);  // 1,769,472 B
    unsigned short* zlo = (unsigned short*)(ws + 16973824);  // 1,769,472 B
    unsigned short* ehi = (unsigned short*)(ws + 18743296);  //   524,288 B
    unsigned short* elo = (unsigned short*)(ws + 19267584);  //   524,288 B
    unsigned long long* pats = (unsigned long long*)(ws + 19791872); // 27,648 B
    int*   idx  = (int*)(ws + 19819520);             // 13,824 B
    float* avgp_part = (float*)(ws + 19833344);      // 54*4096 = 221,184 B
    float* scal = (float*)(ws + 20054528);           // 64 B

    k_pre<<<5344, 256, 0, stream>>>(in_blocks, cb, z_e, pats, scal,
                                    en, ehi, elo, zhi, zlo);
    k_gemm<<<dim3(54, 8), 128, 0, stream>>>(zhi, zlo, ehi, elo, aff);
    k_stats<<<NSB, 256, 0, stream>>>(aff, avgp_part, scal, idx, out + 884737);
    k_ham<<<378, 128, 0, stream>>>(zhi, pats, scal);
    k_zq_final<<<3456, 256, 0, stream>>>(en, idx, avgp_part, scal, out);
}

// Round 6
// 159.468 us; speedup vs baseline: 1.4730x; 1.0244x over previous
//
#include <hip/hip_runtime.h>
#include <cstdint>
#include <cstddef>

#define N_ROWS 3456   // 16*216 chunks
#define C_DIM 256
#define K_CB 1024
#define B_SZ 16
#define SPATIAL 216
#define VOX 13824     // 24*24*24
#define NCH 32
#define NSB 54        // k_post blocks (64 rows each)

typedef __attribute__((ext_vector_type(16))) float f32x16;
typedef __attribute__((ext_vector_type(8))) short bf16x8;

__device__ __forceinline__ unsigned short f2bf_rne(float f) {
    unsigned int u = __float_as_uint(f);
    u += 0x7FFFu + ((u >> 16) & 1u);
    return (unsigned short)(u >> 16);
}
__device__ __forceinline__ float bf2f(unsigned short h) {
    unsigned int u = ((unsigned int)h) << 16;
    return __uint_as_float(u);
}

// ---------------- K1: fused preprocessing: patterns + init + cb/z norm+split
// grid: [0,864) patterns ; [864,1888) codebook ; [1888,5344) z rows
__global__ __launch_bounds__(256) void k_pre(
        const float* __restrict__ in, const float* __restrict__ cb,
        const float* __restrict__ ze,
        unsigned long long* __restrict__ pats,
        float* __restrict__ scal,
        float* __restrict__ en,
        unsigned short* __restrict__ ehi, unsigned short* __restrict__ elo,
        unsigned short* __restrict__ zhi, unsigned short* __restrict__ zlo) {
    int bid = blockIdx.x;
    int t = threadIdx.x;
    if (bid < 864) {
        if (bid == 0 && t < 16) scal[t] = 0.0f;   // scal[0..7] + done counter
        int v = bid * 256 + t;
        int b = v / VOX;
        int r = v % VOX;
        const float* p = in + (size_t)b * NCH * VOX + r;
        float v0 = p[0];
        float mx = -INFINITY;
#pragma unroll
        for (int c = 1; c < NCH; ++c) mx = fmaxf(mx, p[(size_t)c * VOX]);
        unsigned long long m = __ballot(mx > v0);
        if ((t & 63) == 0) pats[v >> 6] = m;
        return;
    }
    __shared__ float ws[4];
    if (bid < 1888) {
        int k = bid - 864, c = t;
        float v = cb[k * C_DIM + c];
        float ss = v * v;
#pragma unroll
        for (int off = 32; off > 0; off >>= 1) ss += __shfl_down(ss, off, 64);
        if ((c & 63) == 0) ws[c >> 6] = ss;
        __syncthreads();
        float nrm = fmaxf(sqrtf(ws[0] + ws[1] + ws[2] + ws[3]), 1e-12f);
        float o = v / nrm;
        en[k * C_DIM + c] = o;
        unsigned short h = f2bf_rne(o);
        ehi[k * C_DIM + c] = h;
        elo[k * C_DIM + c] = f2bf_rne(o - bf2f(h));
    } else {
        int n = bid - 1888, c = t;
        int b = n / SPATIAL, s = n % SPATIAL;
        float v = ze[((size_t)(b * C_DIM + c)) * SPATIAL + s];
        float ss = v * v;
#pragma unroll
        for (int off = 32; off > 0; off >>= 1) ss += __shfl_down(ss, off, 64);
        if ((c & 63) == 0) ws[c >> 6] = ss;
        __syncthreads();
        float nrm = fmaxf(sqrtf(ws[0] + ws[1] + ws[2] + ws[3]), 1e-12f);
        float o = v / nrm;
        unsigned short h = f2bf_rne(o);
        zhi[n * C_DIM + c] = h;
        zlo[n * C_DIM + c] = f2bf_rne(o - bf2f(h));
    }
}

// ------------- K2: fat kernel: affinity GEMM (bf16x3 MFMA) + hamming Gram
// blocks [0,432): gemm 64x128 tiles; [432,810): ham upper-tri 128x128 tiles
#define GS 72
#define HSTR 72
__global__ __launch_bounds__(128) void k_mid(
        const unsigned short* __restrict__ zhi, const unsigned short* __restrict__ zlo,
        const unsigned short* __restrict__ ehi, const unsigned short* __restrict__ elo,
        const unsigned long long* __restrict__ pats,
        float* __restrict__ aff, float* __restrict__ scal) {
    __shared__ __align__(16) char smem[55296];
    int t = threadIdx.x;
    int w = t >> 6, lane = t & 63;
    int bid = blockIdx.x;

    if (bid < 432) {
        // ----- GEMM branch: aff = z @ en^T with hi/lo error compensation
        unsigned short* Ah = (unsigned short*)smem;            // 64*GS
        unsigned short* Al = Ah + 64 * GS;                     // 64*GS
        unsigned short* Bh = (unsigned short*)(smem + 18432);  // 128*GS
        unsigned short* Bl = Bh + 128 * GS;
        int i0 = (bid % 54) * 64, j0 = (bid / 54) * 128;

        f32x16 acc[2][2];
#pragma unroll
        for (int r = 0; r < 2; ++r)
#pragma unroll
            for (int q = 0; q < 2; ++q)
#pragma unroll
                for (int e = 0; e < 16; ++e) acc[r][q][e] = 0.0f;

        for (int ck = 0; ck < 4; ++ck) {
            __syncthreads();
#pragma unroll
            for (int l = 0; l < 4; ++l) {          // A: 64 rows x 8 segs of 16B
                int s = l * 128 + t;
                int row = s >> 3, c8 = s & 7;
                *(float4*)&Ah[row * GS + c8 * 8] =
                    *(const float4*)&zhi[(size_t)(i0 + row) * C_DIM + ck * 64 + c8 * 8];
                *(float4*)&Al[row * GS + c8 * 8] =
                    *(const float4*)&zlo[(size_t)(i0 + row) * C_DIM + ck * 64 + c8 * 8];
            }
#pragma unroll
            for (int l = 0; l < 8; ++l) {          // B: 128 rows x 8 segs
                int s = l * 128 + t;
                int row = s >> 3, c8 = s & 7;
                *(float4*)&Bh[row * GS + c8 * 8] =
                    *(const float4*)&ehi[(size_t)(j0 + row) * C_DIM + ck * 64 + c8 * 8];
                *(float4*)&Bl[row * GS + c8 * 8] =
                    *(const float4*)&elo[(size_t)(j0 + row) * C_DIM + ck * 64 + c8 * 8];
            }
            __syncthreads();

#pragma unroll
            for (int ks = 0; ks < 4; ++ks) {
                int koff = (lane >> 5) * 8 + ks * 16;
                bf16x8 ah[2], al[2], bh[2], bl[2];
#pragma unroll
                for (int r = 0; r < 2; ++r) {
                    ah[r] = *(bf16x8*)&Ah[(r * 32 + (lane & 31)) * GS + koff];
                    al[r] = *(bf16x8*)&Al[(r * 32 + (lane & 31)) * GS + koff];
                }
#pragma unroll
                for (int q = 0; q < 2; ++q) {
                    bh[q] = *(bf16x8*)&Bh[(w * 64 + q * 32 + (lane & 31)) * GS + koff];
                    bl[q] = *(bf16x8*)&Bl[(w * 64 + q * 32 + (lane & 31)) * GS + koff];
                }
#pragma unroll
                for (int r = 0; r < 2; ++r)
#pragma unroll
                    for (int q = 0; q < 2; ++q) {
                        acc[r][q] = __builtin_amdgcn_mfma_f32_32x32x16_bf16(ah[r], bh[q], acc[r][q], 0, 0, 0);
                        acc[r][q] = __builtin_amdgcn_mfma_f32_32x32x16_bf16(ah[r], bl[q], acc[r][q], 0, 0, 0);
                        acc[r][q] = __builtin_amdgcn_mfma_f32_32x32x16_bf16(al[r], bh[q], acc[r][q], 0, 0, 0);
                    }
            }
        }
        // C/D layout (m74/m101): col=lane&31, row=(g&3)+8*(g>>2)+4*(lane>>5)
#pragma unroll
        for (int r = 0; r < 2; ++r)
#pragma unroll
            for (int q = 0; q < 2; ++q)
#pragma unroll
                for (int g = 0; g < 16; ++g) {
                    int row = i0 + r * 32 + (g & 3) + 8 * (g >> 2) + 4 * (lane >> 5);
                    int col = j0 + w * 64 + q * 32 + (lane & 31);
                    aff[(size_t)row * K_CB + col] = acc[r][q][g];
                }
        return;
    }

    // ----- HAM branch: pairwise Gram, upper-triangular 128x128 tiles
    unsigned short* zi = (unsigned short*)smem;       // 128*HSTR
    unsigned short* zj = zi + 128 * HSTR;
    int hb = bid - 432;              // 0..377
    int ti = 0, rem = hb;
    while (rem >= 27 - ti) { rem -= 27 - ti; ++ti; }
    int tj = ti + rem;
    int i0 = ti * 128, j0 = tj * 128;
    float factor = (ti == tj) ? 1.0f : 2.0f;

    f32x16 acc[2][4];
#pragma unroll
    for (int a = 0; a < 2; ++a)
#pragma unroll
        for (int b = 0; b < 4; ++b)
#pragma unroll
            for (int e = 0; e < 16; ++e) acc[a][b][e] = 0.0f;

    for (int ck = 0; ck < 4; ++ck) {
        __syncthreads();
#pragma unroll
        for (int p = 0; p < 8; ++p) {
            int row = p * 16 + (t >> 3);
            int seg = t & 7;
            *(float4*)&zi[row * HSTR + seg * 8] =
                *(const float4*)&zhi[(size_t)(i0 + row) * C_DIM + ck * 64 + seg * 8];
            *(float4*)&zj[row * HSTR + seg * 8] =
                *(const float4*)&zhi[(size_t)(j0 + row) * C_DIM + ck * 64 + seg * 8];
        }
        __syncthreads();

#pragma unroll
        for (int ks = 0; ks < 4; ++ks) {
            int off = (lane & 31) * HSTR + (lane >> 5) * 8 + ks * 16;
            bf16x8 a0 = *(bf16x8*)&zi[(w * 64) * HSTR + off];
            bf16x8 a1 = *(bf16x8*)&zi[(w * 64 + 32) * HSTR + off];
            bf16x8 bf[4];
#pragma unroll
            for (int c = 0; c < 4; ++c)
                bf[c] = *(bf16x8*)&zj[(c * 32) * HSTR + off];
#pragma unroll
            for (int c = 0; c < 4; ++c) {
                acc[0][c] = __builtin_amdgcn_mfma_f32_32x32x16_bf16(a0, bf[c], acc[0][c], 0, 0, 0);
                acc[1][c] = __builtin_amdgcn_mfma_f32_32x32x16_bf16(a1, bf[c], acc[1][c], 0, 0, 0);
            }
        }
    }

    unsigned long long pj[4];
#pragma unroll
    for (int c = 0; c < 4; ++c) pj[c] = pats[j0 + c * 32 + (lane & 31)];

    float sW = 0.0f, sD = 0.0f;
#pragma unroll
    for (int r = 0; r < 2; ++r) {
        int ibase = i0 + w * 64 + r * 32 + 4 * (lane >> 5);
#pragma unroll
        for (int g = 0; g < 16; ++g) {
            int gi = ibase + (g & 3) + 8 * (g >> 2);
            unsigned long long pi = pats[gi];
#pragma unroll
            for (int c = 0; c < 4; ++c) {
                int gj = j0 + c * 32 + (lane & 31);
                int pop = __popcll(pi ^ pj[c]);
                float wgt = (pop <= 5 && gi != gj) ? (1.0f - (float)pop * 0.015625f) : 0.0f;
                sW += wgt;
                sD += wgt * acc[r][c][g];
            }
        }
    }
#pragma unroll
    for (int off = 32; off > 0; off >>= 1) {
        sW += __shfl_down(sW, off, 64);
        sD += __shfl_down(sD, off, 64);
    }
    if (lane == 0) {
        atomicAdd(&scal[2], factor * sW);
        atomicAdd(&scal[3], factor * sD);
    }
}

// -------- K3: stats + z_q gather/scatter + final loss (last-block reduce)
// 54 blocks x 64 rows; wave = 16 rows; lane owns 16 cols. Gather en[idx]
// rows into LDS transpose buffer (stride 257 -> conflict-free), write
// coalesced. Last block (atomic done counter) reduces avgp partials + loss.
#define ZQS 257
__global__ __launch_bounds__(256) void k_post(
        const float* __restrict__ aff, const float* __restrict__ en,
        float* __restrict__ avgp_part, float* __restrict__ scal,
        float* __restrict__ out) {
    __shared__ float lps[4][K_CB];       // 16 KB
    __shared__ float zq[64 * ZQS];       // 65.8 KB transpose buffer
    __shared__ float lsc[8];
    __shared__ float ws4[4];
    __shared__ int lastflag;
    unsigned int* done = (unsigned int*)&scal[8];
    int t = threadIdx.x;
    int lane = t & 63, w = t >> 6;
    int n0 = blockIdx.x * 64 + w * 16;

    float ps[16];
#pragma unroll
    for (int i = 0; i < 16; ++i) ps[i] = 0.0f;
    float se = 0.0f, cm = 0.0f;

    for (int r = 0; r < 16; ++r) {
        int row = n0 + r;
        const float* ap = aff + (size_t)row * K_CB;
        float4 v[4];
#pragma unroll
        for (int j = 0; j < 4; ++j)
            v[j] = *(const float4*)&ap[j * 256 + lane * 4];

        float m = v[0].x; int mi = lane * 4;
#pragma unroll
        for (int j = 0; j < 4; ++j)
#pragma unroll
            for (int i = 0; i < 4; ++i) {
                float x = ((const float*)&v[j])[i];
                int col = j * 256 + lane * 4 + i;
                if (x > m) { m = x; mi = col; }
            }
#pragma unroll
        for (int off = 32; off > 0; off >>= 1) {
            float vo = __shfl_down(m, off, 64);
            int   io = __shfl_down(mi, off, 64);
            if (vo > m || (vo == m && io < mi)) { m = vo; mi = io; }
        }
        m = __shfl(m, 0, 64);
        mi = __shfl(mi, 0, 64);

        float e[16];
        float S = 0.0f, T = 0.0f;
#pragma unroll
        for (int j = 0; j < 4; ++j)
#pragma unroll
            for (int i = 0; i < 4; ++i) {
                float d = 100.0f * (((const float*)&v[j])[i] - m);
                float ee = __expf(d);
                e[j * 4 + i] = ee; S += ee; T += ee * d;
            }
#pragma unroll
        for (int off = 32; off > 0; off >>= 1) {
            S += __shfl_down(S, off, 64);
            T += __shfl_down(T, off, 64);
        }
        S = __shfl(S, 0, 64);
        T = __shfl(T, 0, 64);
        float invS = 1.0f / S;
#pragma unroll
        for (int i = 0; i < 16; ++i) ps[i] += e[i] * invS;
        se += logf(S) - T * invS;
        cm += 2.0f - 2.0f * m;
        if (lane == 0) out[884737 + row] = (float)mi;

        // gather en[mi] row into transpose buffer (local row = w*16+r)
        float4 g4 = *(const float4*)&en[(size_t)mi * C_DIM + lane * 4];
        int lr = w * 16 + r;
        zq[lr * ZQS + lane * 4 + 0] = g4.x;
        zq[lr * ZQS + lane * 4 + 1] = g4.y;
        zq[lr * ZQS + lane * 4 + 2] = g4.z;
        zq[lr * ZQS + lane * 4 + 3] = g4.w;
    }

    // aggregate ps across waves; write per-block avgp partial (plain stores)
#pragma unroll
    for (int j = 0; j < 4; ++j)
#pragma unroll
        for (int i = 0; i < 4; ++i)
            lps[w][j * 256 + lane * 4 + i] = ps[j * 4 + i];
    if (lane == 0) { lsc[w] = se; lsc[4 + w] = cm; }
    __syncthreads();
#pragma unroll
    for (int c = 0; c < 4; ++c) {
        int col = t * 4 + c;
        avgp_part[(size_t)blockIdx.x * K_CB + col] =
            lps[0][col] + lps[1][col] + lps[2][col] + lps[3][col];
    }
    if (t == 0) atomicAdd(&scal[0], lsc[0] + lsc[1] + lsc[2] + lsc[3]);
    if (t == 1) atomicAdd(&scal[1], lsc[4] + lsc[5] + lsc[6] + lsc[7]);

    // coalesced z_q write: wave handles one col per iter, lanes = 64 rows
    {
        int n = blockIdx.x * 64 + lane;
        int b = n / SPATIAL, s = n - b * SPATIAL;
        size_t obase = ((size_t)b * C_DIM) * SPATIAL + s;
        for (int cc = 0; cc < 64; ++cc) {
            int c = cc * 4 + w;
            out[obase + (size_t)c * SPATIAL] = zq[lane * ZQS + c];
        }
    }

    // last block computes avg-entropy + final loss
    __syncthreads();
    if (t == 0) {
        __threadfence();
        unsigned int old = atomicAdd(done, 1u);
        lastflag = (old == NSB - 1) ? 1 : 0;
    }
    __syncthreads();
    if (lastflag) {
        __threadfence();
        float term = 0.0f;
#pragma unroll
        for (int j = 0; j < 4; ++j) {
            int col = t + 256 * j;
            float ap = 0.0f;
            for (int bb = 0; bb < NSB; ++bb)
                ap += avgp_part[(size_t)bb * K_CB + col];
            ap *= (1.0f / N_ROWS);
            term += ap * logf(ap + 1e-5f);
        }
#pragma unroll
        for (int off = 32; off > 0; off >>= 1) term += __shfl_down(term, off, 64);
        if ((t & 63) == 0) ws4[t >> 6] = term;
        __syncthreads();
        if (t == 0) {
            float sAP = ws4[0] + ws4[1] + ws4[2] + ws4[3];
            float s0 = atomicAdd(&scal[0], 0.0f);
            float s1 = atomicAdd(&scal[1], 0.0f);
            float s2 = atomicAdd(&scal[2], 0.0f);
            float s3 = atomicAdd(&scal[3], 0.0f);
            float sample = s0 * (1.0f / N_ROWS);
            float commit = s1 * (1.0f / ((float)N_ROWS * C_DIM));
            float ent = 0.1f * (sample + sAP);
            float ham = (s2 - s3) / (s2 + 1e-8f);
            out[884736] = 1.25f * commit + ent + ham;
        }
    }
}

// ----------------------------------------------------------------- launch
extern "C" void kernel_launch(void* const* d_in, const int* in_sizes, int n_in,
                              void* d_out, int out_size, void* d_ws, size_t ws_size,
                              hipStream_t stream) {
    const float* in_blocks = (const float*)d_in[0];  // [16,32,24,24,24]
    const float* z_e       = (const float*)d_in[1];  // [16,256,6,6,6]
    const float* cb        = (const float*)d_in[2];  // [1024,256]
    float* out = (float*)d_out;  // [884736 z_q][1 loss][3456 idx]

    char* ws = (char*)d_ws;
    float* en   = (float*)(ws + 0);                  //  1,048,576 B
    float* aff  = (float*)(ws + 1048576);            // 14,155,776 B
    unsigned short* zhi = (unsigned short*)(ws + 15204352);  // 1,769,472 B
    unsigned short* zlo = (unsigned short*)(ws + 16973824);  // 1,769,472 B
    unsigned short* ehi = (unsigned short*)(ws + 18743296);  //   524,288 B
    unsigned short* elo = (unsigned short*)(ws + 19267584);  //   524,288 B
    unsigned long long* pats = (unsigned long long*)(ws + 19791872); // 27,648 B
    float* avgp_part = (float*)(ws + 19819520);      // 54*4096 = 221,184 B
    float* scal = (float*)(ws + 20040704);           // 64 B (scal[0..7] + done)

    k_pre<<<5344, 256, 0, stream>>>(in_blocks, cb, z_e, pats, scal,
                                    en, ehi, elo, zhi, zlo);
    k_mid<<<810, 128, 0, stream>>>(zhi, zlo, ehi, elo, pats, aff, scal);
    k_post<<<NSB, 256, 0, stream>>>(aff, en, avgp_part, scal, out);
}